// Round 1
// baseline (133.848 us; speedup 1.0000x reference)
//
#include <hip/hip_runtime.h>

// Problem constants (from reference): S = 256*256 = 65536, B = 1024.
// z: (B,S) f32; W: (1,S,1) f32; bias: (S,) f32; b: scalar (unused).
// out[i,j] = (z[i,:] . w) * w[j] + bias[j], f32.

#define SDIM 65536
#define S4   (SDIM / 4)   // 16384 float4 per row

__global__ __launch_bounds__(512) void row_dot_kernel(
    const float* __restrict__ z,
    const float* __restrict__ w,
    float* __restrict__ scal)
{
    const int row = blockIdx.x;
    const float4* __restrict__ zrow =
        reinterpret_cast<const float4*>(z + (size_t)row * SDIM);
    const float4* __restrict__ w4 = reinterpret_cast<const float4*>(w);

    float acc = 0.0f;
    // 512 threads, 16384 float4 -> 32 iterations, coalesced 16B/lane.
    for (int i = threadIdx.x; i < S4; i += 512) {
        float4 a = zrow[i];
        float4 b = w4[i];
        acc += a.x * b.x + a.y * b.y + a.z * b.z + a.w * b.w;
    }

    // wave-64 butterfly reduce
    #pragma unroll
    for (int off = 32; off > 0; off >>= 1)
        acc += __shfl_down(acc, off, 64);

    __shared__ float smem[8];
    const int lane = threadIdx.x & 63;
    const int wid  = threadIdx.x >> 6;
    if (lane == 0) smem[wid] = acc;
    __syncthreads();
    if (threadIdx.x == 0) {
        float t = 0.0f;
        #pragma unroll
        for (int i = 0; i < 8; ++i) t += smem[i];
        scal[row] = t;
    }
}

__global__ __launch_bounds__(256) void outer_kernel(
    const float* __restrict__ scal,
    const float* __restrict__ w,
    const float* __restrict__ bias,
    float* __restrict__ out,
    int total4)
{
    const float4* __restrict__ w4 = reinterpret_cast<const float4*>(w);
    const float4* __restrict__ b4 = reinterpret_cast<const float4*>(bias);
    float4* __restrict__ o4 = reinterpret_cast<float4*>(out);

    const int stride = gridDim.x * blockDim.x;
    for (int idx = blockIdx.x * blockDim.x + threadIdx.x; idx < total4;
         idx += stride) {
        const int row = idx >> 14;        // / S4
        const int j   = idx & (S4 - 1);   // % S4
        const float s = scal[row];
        float4 wv = w4[j];
        float4 bv = b4[j];
        float4 r;
        r.x = fmaf(s, wv.x, bv.x);
        r.y = fmaf(s, wv.y, bv.y);
        r.z = fmaf(s, wv.z, bv.z);
        r.w = fmaf(s, wv.w, bv.w);
        o4[idx] = r;
    }
}

extern "C" void kernel_launch(void* const* d_in, const int* in_sizes, int n_in,
                              void* d_out, int out_size, void* d_ws, size_t ws_size,
                              hipStream_t stream)
{
    const float* z    = (const float*)d_in[0];
    const float* w    = (const float*)d_in[1];  // (1,S,1) flat == (S,)
    const float* bias = (const float*)d_in[2];
    float* out  = (float*)d_out;
    float* scal = (float*)d_ws;                 // B floats of scratch

    const int B = in_sizes[0] / SDIM;           // 1024

    row_dot_kernel<<<B, 512, 0, stream>>>(z, w, scal);

    const int total4 = B * S4;                  // 16,777,216
    const int blocks = 2048;                    // grid-stride, ~32 iters/thread
    outer_kernel<<<blocks, 256, 0, stream>>>(scal, w, bias, out, total4);
}